// Round 2
// baseline (311.634 us; speedup 1.0000x reference)
//
#include <hip/hip_runtime.h>

// ROIAlign forward (PH=PW=7, SCALE=0.25, SR=2, ALIGNED=true)
//   input [4,256,200,200] fp32 NCHW, rois [512,5], out [512,256,7,7] fp32
//
// Two-pass design:
//   Pass 1: NCHW -> NHWC transpose into d_ws (164 MB). All 256 channels of a
//           pixel become contiguous, so ROI gathers coalesce across channels.
//   Pass 2: block = (roi, channel-half). Wave = 64 lanes x float2 = one bin's
//           128 channels; each bilinear corner is ONE contiguous 512B load
//           (vs ~20 scattered lines/load in the NCHW baseline -> ~5x fewer
//           TA line-transactions, which round-1 counters showed is the real
//           bottleneck: replay dispatches were LLC-resident (FETCH~0) at the
//           identical 138us).
//   Results staged in LDS, written out as one contiguous region per block
//   (direct NCHW stores would scatter 64 lanes over stride-196B lines).
//
// Fallback: if ws_size < 164 MB, run the round-1 single-pass kernel.

#define R_PH 7
#define R_PW 7
#define R_SR 2
#define R_SCALE 0.25f
#define R_B 4
#define R_C 256
#define R_H 200
#define R_W 200
#define R_HW (R_H * R_W)

__device__ __forceinline__ void axis_sample(float start, float bin, int p, int s, int size,
                                            int& lo, int& hi, float& wlo, float& whi) {
    // coord = start + p*bin + (s+0.5)*bin/SR   (same grouping as reference)
    float coord = (start + (float)p * bin) + ((float)s + 0.5f) * bin * (1.0f / R_SR);
    bool valid = (coord >= -1.0f) && (coord <= (float)size);
    float c = fmaxf(coord, 0.0f);
    int lo_raw = (int)floorf(c);
    bool at_edge = lo_raw >= size - 1;
    lo = at_edge ? size - 1 : lo_raw;
    hi = at_edge ? size - 1 : lo_raw + 1;
    float cv = at_edge ? (float)(size - 1) : c;
    float frac = cv - (float)lo;          // weight toward hi
    whi = valid ? frac : 0.0f;
    wlo = valid ? (1.0f - frac) : 0.0f;
}

// ---------------- Pass 1: NCHW -> NHWC transpose ----------------
// Per batch: [C=256, P=40000] -> [P, C]. 64x64 tiles via LDS.
__global__ void __launch_bounds__(512)
nchw_to_nhwc(const float* __restrict__ in, float* __restrict__ out) {
    __shared__ float tile[64][65];
    int p0 = blockIdx.x * 64;   // 625 tiles cover P=40000 exactly
    int c0 = blockIdx.y * 64;   // 4 tiles cover C=256
    int b  = blockIdx.z;
    int tx = threadIdx.x;       // 0..63
    int ty = threadIdx.y;       // 0..7
    const float* src = in + (size_t)b * R_C * R_HW;
    float* dst = out + (size_t)b * R_HW * R_C;
#pragma unroll
    for (int i = 0; i < 64; i += 8)
        tile[ty + i][tx] = src[(size_t)(c0 + ty + i) * R_HW + p0 + tx];
    __syncthreads();
#pragma unroll
    for (int i = 0; i < 64; i += 8)
        dst[(size_t)(p0 + ty + i) * R_C + c0 + tx] = tile[tx][ty + i];
}

// ---------------- Pass 2: gather from NHWC ----------------
// Grid (N, 2). Block 256 = 4 waves; wave w handles bins w, w+4, ...
// Lane l covers local channels 2l, 2l+1 (float2).
#define LDS_STRIDE 130   // 128 channels + 2 pad (keeps float2 align, breaks bank stride)

__global__ void __launch_bounds__(256)
roi_align_nhwc(const float* __restrict__ feat,   // [B,H,W,C]
               const float* __restrict__ rois,
               float* __restrict__ out) {
    __shared__ float lds[49 * LDS_STRIDE];
    int n     = blockIdx.x;
    int chalf = blockIdx.y;            // 0 or 1
    int t    = threadIdx.x;
    int wave = t >> 6;
    int lane = t & 63;
    int cl   = lane * 2;               // local channel (0..126)
    int c    = chalf * 128 + cl;

    const float* r = rois + (size_t)n * 5;
    int   b  = (int)r[0];
    float sx = r[1] * R_SCALE - 0.5f;
    float sy = r[2] * R_SCALE - 0.5f;
    float ex = r[3] * R_SCALE - 0.5f;
    float ey = r[4] * R_SCALE - 0.5f;
    float bin_w = (ex - sx) * (1.0f / R_PW);
    float bin_h = (ey - sy) * (1.0f / R_PH);

    const float* base = feat + (size_t)b * R_HW * R_C + c;

    for (int bin = wave; bin < R_PH * R_PW; bin += 4) {
        int ph = bin / 7;
        int pw = bin - ph * 7;

        int   ylo[R_SR], yhi[R_SR], xlo[R_SR], xhi[R_SR];
        float wyl[R_SR], wyh[R_SR], wxl[R_SR], wxh[R_SR];
#pragma unroll
        for (int s = 0; s < R_SR; ++s) {
            axis_sample(sy, bin_h, ph, s, R_H, ylo[s], yhi[s], wyl[s], wyh[s]);
            axis_sample(sx, bin_w, pw, s, R_W, xlo[s], xhi[s], wxl[s], wxh[s]);
        }

        float accx = 0.0f, accy = 0.0f;
#pragma unroll
        for (int ys = 0; ys < R_SR; ++ys) {
#pragma unroll
            for (int xs = 0; xs < R_SR; ++xs) {
                const float2 fll = *(const float2*)(base + (size_t)(ylo[ys] * R_W + xlo[xs]) * R_C);
                const float2 flh = *(const float2*)(base + (size_t)(ylo[ys] * R_W + xhi[xs]) * R_C);
                const float2 fhl = *(const float2*)(base + (size_t)(yhi[ys] * R_W + xlo[xs]) * R_C);
                const float2 fhh = *(const float2*)(base + (size_t)(yhi[ys] * R_W + xhi[xs]) * R_C);
                accx += wyl[ys] * (wxl[xs] * fll.x + wxh[xs] * flh.x)
                      + wyh[ys] * (wxl[xs] * fhl.x + wxh[xs] * fhh.x);
                accy += wyl[ys] * (wxl[xs] * fll.y + wxh[xs] * flh.y)
                      + wyh[ys] * (wxl[xs] * fhl.y + wxh[xs] * fhh.y);
            }
        }
        float2 res;
        res.x = accx * (1.0f / (R_SR * R_SR));
        res.y = accy * (1.0f / (R_SR * R_SR));
        *(float2*)&lds[bin * LDS_STRIDE + cl] = res;
    }
    __syncthreads();

    // Contiguous write-out: out[n*12544 + chalf*6272 + (ch*49 + bin)]
    float* outn = out + (size_t)n * (R_C * 49) + (size_t)chalf * (128 * 49);
    for (int i = t; i < 128 * 49; i += 256) {
        int ch  = i / 49;
        int bin = i - ch * 49;
        outn[i] = lds[bin * LDS_STRIDE + ch];
    }
}

// ---------------- Fallback: round-1 single-pass kernel ----------------
__global__ void __launch_bounds__(256)
roi_align_fwd(const float* __restrict__ input,
              const float* __restrict__ rois,
              float* __restrict__ out, int total) {
    int idx = blockIdx.x * blockDim.x + threadIdx.x;
    if (idx >= total) return;

    int pw = idx % R_PW;
    int ph = (idx / R_PW) % R_PH;
    int c  = (idx / (R_PW * R_PH)) % R_C;
    int n  = idx / (R_PW * R_PH * R_C);

    const float* r = rois + (size_t)n * 5;
    int   b  = (int)r[0];
    float sx = r[1] * R_SCALE - 0.5f;
    float sy = r[2] * R_SCALE - 0.5f;
    float ex = r[3] * R_SCALE - 0.5f;
    float ey = r[4] * R_SCALE - 0.5f;
    float bin_w = (ex - sx) * (1.0f / R_PW);
    float bin_h = (ey - sy) * (1.0f / R_PH);

    const float* plane = input + (size_t)(b * R_C + c) * R_HW;

    int   ylo[R_SR], yhi[R_SR], xlo[R_SR], xhi[R_SR];
    float wylo[R_SR], wyhi[R_SR], wxlo[R_SR], wxhi[R_SR];
#pragma unroll
    for (int s = 0; s < R_SR; ++s) {
        axis_sample(sy, bin_h, ph, s, R_H, ylo[s], yhi[s], wylo[s], wyhi[s]);
        axis_sample(sx, bin_w, pw, s, R_W, xlo[s], xhi[s], wxlo[s], wxhi[s]);
    }

    float acc = 0.0f;
#pragma unroll
    for (int ys = 0; ys < R_SR; ++ys) {
        const float* row_lo = plane + ylo[ys] * R_W;
        const float* row_hi = plane + yhi[ys] * R_W;
#pragma unroll
        for (int xs = 0; xs < R_SR; ++xs) {
            acc += wylo[ys] * (wxlo[xs] * row_lo[xlo[xs]] + wxhi[xs] * row_lo[xhi[xs]])
                 + wyhi[ys] * (wxlo[xs] * row_hi[xlo[xs]] + wxhi[xs] * row_hi[xhi[xs]]);
        }
    }
    out[idx] = acc * (1.0f / (R_SR * R_SR));
}

extern "C" void kernel_launch(void* const* d_in, const int* in_sizes, int n_in,
                              void* d_out, int out_size, void* d_ws, size_t ws_size,
                              hipStream_t stream) {
    const float* input = (const float*)d_in[0];
    const float* rois  = (const float*)d_in[1];
    float* out = (float*)d_out;
    int N = in_sizes[1] / 5;

    const size_t ws_needed = (size_t)R_B * R_C * R_HW * sizeof(float);  // 163.84 MB
    if (ws_size >= ws_needed) {
        float* nhwc = (float*)d_ws;
        dim3 tgrid(R_HW / 64, R_C / 64, R_B);     // 625 x 4 x 4
        dim3 tblock(64, 8);
        nchw_to_nhwc<<<tgrid, tblock, 0, stream>>>(input, nhwc);
        dim3 ggrid(N, 2);
        roi_align_nhwc<<<ggrid, 256, 0, stream>>>(nhwc, rois, out);
    } else {
        int total = out_size;
        roi_align_fwd<<<(total + 255) / 256, 256, 0, stream>>>(input, rois, out, total);
    }
}

// Round 3
// 260.078 us; speedup vs baseline: 1.1982x; 1.1982x over previous
//
#include <hip/hip_runtime.h>

// ROIAlign forward (PH=PW=7, SCALE=0.25, SR=2, ALIGNED=true)
//   input [4,256,200,200] fp32 NCHW, rois [512,5], out [512,256,7,7] fp32
//
// Round-3 design: fused strip-LDS gather (no global relayout).
//   - Round-1/2 evidence: kernel is gather-transaction-bound, not HBM-bound
//     (replay ran FETCH~0 at identical time); a full NHWC transpose costs
//     ~100us of pure BW and erased the gather win (146us total vs 138us).
//   - Here each block = (c, b, y-strip): stages a 56-row x 200-col strip of
//     one channel plane into LDS (44.8 KB) with coalesced float4 reads (no
//     write-back), then computes all (roi, ph) bins of batch b whose row
//     span falls in the strip. All 16 bilinear taps become LDS reads.
//   - Strip assignment is integer-safe: for sample s=0 of a bin, lo0 is the
//     MINIMUM row touched (coords monotone in s, binh>=0); max row <= lo0+5
//     (binh <= 64/7 -> span 0.5*binh+2 < 6; edge-clamp keeps <=199). Strip
//     = lo0/50, staged rows [50s, 50s+55] always cover the taps.
//   - 44.8 KB LDS -> 3 blocks/CU -> staging overlaps compute across blocks.
//   - Tiny single-block pre-kernel builds per-(batch,strip) worklists in d_ws.
// Fixed harness overhead (~165us: d_ws 640MB poison + input restore + out
// poison) is untouchable; target is kernel-sum 146us -> ~45us.

#define R_PH 7
#define R_PW 7
#define R_SR 2
#define R_SCALE 0.25f
#define R_C 256
#define R_H 200
#define R_W 200
#define R_HW (R_H * R_W)
#define STRIP 50
#define NSTRIP 4
#define STAGE_ROWS 56   // covers rmin in [50s, 50s+49] + span 5

__device__ __forceinline__ void axis_sample(float start, float bin, int p, int s, int size,
                                            int& lo, int& hi, float& wlo, float& whi) {
    // coord = start + p*bin + (s+0.5)*bin/SR   (same grouping as reference)
    float coord = (start + (float)p * bin) + ((float)s + 0.5f) * bin * (1.0f / R_SR);
    bool valid = (coord >= -1.0f) && (coord <= (float)size);
    float c = fmaxf(coord, 0.0f);
    int lo_raw = (int)floorf(c);
    bool at_edge = lo_raw >= size - 1;
    lo = at_edge ? size - 1 : lo_raw;
    hi = at_edge ? size - 1 : lo_raw + 1;
    float cv = at_edge ? (float)(size - 1) : c;
    float frac = cv - (float)lo;          // weight toward hi
    whi = valid ? frac : 0.0f;
    wlo = valid ? (1.0f - frac) : 0.0f;
}

// ---------- Pre-kernel: build per-(batch,strip) lists of (roi, ph) ----------
// ws layout: int cnt[16]; int lists[16][N*7]
__global__ void __launch_bounds__(512)
build_lists(const float* __restrict__ rois, int N, int* __restrict__ ws) {
    __shared__ int lcnt[NSTRIP * 4];
    int t = threadIdx.x;
    if (t < 16) lcnt[t] = 0;
    __syncthreads();
    int* lists = ws + 16;
    for (int n = t; n < N; n += 512) {
        const float* r = rois + (size_t)n * 5;
        int b = (int)r[0];
        float sy = r[2] * R_SCALE - 0.5f;
        float ey = r[4] * R_SCALE - 0.5f;
        float binh = (ey - sy) * (1.0f / R_PH);
        for (int ph = 0; ph < R_PH; ++ph) {
            int lo, hi; float wl, wh;
            axis_sample(sy, binh, ph, 0, R_H, lo, hi, wl, wh);  // s=0 lo == min row
            int bs = b * NSTRIP + lo / STRIP;                   // lo in [0,199]
            int pos = atomicAdd(&lcnt[bs], 1);
            lists[bs * (N * R_PH) + pos] = (n << 3) | ph;
        }
    }
    __syncthreads();
    if (t < 16) ws[t] = lcnt[t];
}

// ---------- Main: strip-LDS gather ----------
// grid (C=256, B=4, NSTRIP=4), block 512
__global__ void __launch_bounds__(512)
roi_strip(const float* __restrict__ input,
          const float* __restrict__ rois,
          const int* __restrict__ ws, int N,
          float* __restrict__ out) {
    __shared__ float pl[STAGE_ROWS * R_W];   // 44800 B -> 3 blocks/CU
    int c = blockIdx.x;
    int b = blockIdx.y;
    int s = blockIdx.z;
    int r0 = s * STRIP;
    int nrows = min(STAGE_ROWS, R_H - r0);

    const float4* src = (const float4*)(input + (size_t)(b * R_C + c) * R_HW + r0 * R_W);
    float4* dstv = (float4*)pl;
    int nf4 = nrows * (R_W / 4);
    for (int i = threadIdx.x; i < nf4; i += 512) dstv[i] = src[i];

    int m = ws[b * NSTRIP + s];
    const int* list = ws + 16 + (b * NSTRIP + s) * (N * R_PH);
    __syncthreads();

    int total = m * R_PW;
    for (int i = threadIdx.x; i < total; i += 512) {
        int e  = i / R_PW;
        int pw = i - e * R_PW;
        int code = list[e];
        int n  = code >> 3;
        int ph = code & 7;
        const float* r = rois + (size_t)n * 5;
        float sx = r[1] * R_SCALE - 0.5f;
        float sy = r[2] * R_SCALE - 0.5f;
        float ex = r[3] * R_SCALE - 0.5f;
        float ey = r[4] * R_SCALE - 0.5f;
        float binw = (ex - sx) * (1.0f / R_PW);
        float binh = (ey - sy) * (1.0f / R_PH);

        int   ylo[R_SR], yhi[R_SR], xlo[R_SR], xhi[R_SR];
        float wyl[R_SR], wyh[R_SR], wxl[R_SR], wxh[R_SR];
#pragma unroll
        for (int q = 0; q < R_SR; ++q) {
            axis_sample(sy, binh, ph, q, R_H, ylo[q], yhi[q], wyl[q], wyh[q]);
            axis_sample(sx, binw, pw, q, R_W, xlo[q], xhi[q], wxl[q], wxh[q]);
        }

        float acc = 0.0f;
#pragma unroll
        for (int ys = 0; ys < R_SR; ++ys) {
            const float* rlo = pl + (ylo[ys] - r0) * R_W;
            const float* rhi = pl + (yhi[ys] - r0) * R_W;
#pragma unroll
            for (int xs = 0; xs < R_SR; ++xs) {
                acc += wyl[ys] * (wxl[xs] * rlo[xlo[xs]] + wxh[xs] * rlo[xhi[xs]])
                     + wyh[ys] * (wxl[xs] * rhi[xlo[xs]] + wxh[xs] * rhi[xhi[xs]]);
            }
        }
        out[(size_t)(n * R_C + c) * 49 + ph * R_PW + pw] = acc * 0.25f;
    }
}

// ---------- Fallback: round-1 single-pass kernel (if ws too small) ----------
__global__ void __launch_bounds__(256)
roi_align_fwd(const float* __restrict__ input,
              const float* __restrict__ rois,
              float* __restrict__ out, int total) {
    int idx = blockIdx.x * blockDim.x + threadIdx.x;
    if (idx >= total) return;
    int pw = idx % R_PW;
    int ph = (idx / R_PW) % R_PH;
    int c  = (idx / (R_PW * R_PH)) % R_C;
    int n  = idx / (R_PW * R_PH * R_C);
    const float* r = rois + (size_t)n * 5;
    int   b  = (int)r[0];
    float sx = r[1] * R_SCALE - 0.5f;
    float sy = r[2] * R_SCALE - 0.5f;
    float ex = r[3] * R_SCALE - 0.5f;
    float ey = r[4] * R_SCALE - 0.5f;
    float bin_w = (ex - sx) * (1.0f / R_PW);
    float bin_h = (ey - sy) * (1.0f / R_PH);
    const float* plane = input + (size_t)(b * R_C + c) * R_HW;
    int   ylo[R_SR], yhi[R_SR], xlo[R_SR], xhi[R_SR];
    float wylo[R_SR], wyhi[R_SR], wxlo[R_SR], wxhi[R_SR];
#pragma unroll
    for (int s = 0; s < R_SR; ++s) {
        axis_sample(sy, bin_h, ph, s, R_H, ylo[s], yhi[s], wylo[s], wyhi[s]);
        axis_sample(sx, bin_w, pw, s, R_W, xlo[s], xhi[s], wxlo[s], wxhi[s]);
    }
    float acc = 0.0f;
#pragma unroll
    for (int ys = 0; ys < R_SR; ++ys) {
        const float* row_lo = plane + ylo[ys] * R_W;
        const float* row_hi = plane + yhi[ys] * R_W;
#pragma unroll
        for (int xs = 0; xs < R_SR; ++xs) {
            acc += wylo[ys] * (wxlo[xs] * row_lo[xlo[xs]] + wxhi[xs] * row_lo[xhi[xs]])
                 + wyhi[ys] * (wxlo[xs] * row_hi[xlo[xs]] + wxhi[xs] * row_hi[xhi[xs]]);
        }
    }
    out[idx] = acc * (1.0f / (R_SR * R_SR));
}

extern "C" void kernel_launch(void* const* d_in, const int* in_sizes, int n_in,
                              void* d_out, int out_size, void* d_ws, size_t ws_size,
                              hipStream_t stream) {
    const float* input = (const float*)d_in[0];
    const float* rois  = (const float*)d_in[1];
    float* out = (float*)d_out;
    int N = in_sizes[1] / 5;

    size_t ws_needed = (size_t)(16 + 16 * N * R_PH) * sizeof(int);  // ~230 KB @ N=512
    if (ws_size >= ws_needed) {
        int* ws = (int*)d_ws;
        build_lists<<<1, 512, 0, stream>>>(rois, N, ws);
        dim3 grid(R_C, 4, NSTRIP);          // c, b, strip
        roi_strip<<<grid, 512, 0, stream>>>(input, rois, ws, N, out);
    } else {
        int total = out_size;
        roi_align_fwd<<<(total + 255) / 256, 256, 0, stream>>>(input, rois, out, total);
    }
}